// Round 3
// baseline (143.974 us; speedup 1.0000x reference)
//
#include <hip/hip_runtime.h>
#include <hip/hip_bf16.h>

#define HW_TOTAL 16384
#define C2 128
#define PPB 8
#define NBLK (HW_TOTAL / PPB)

typedef short bf16x8 __attribute__((ext_vector_type(8)));
typedef float f32x4 __attribute__((ext_vector_type(4)));

__device__ __forceinline__ unsigned pk2bf(float lo, float hi) {
    __hip_bfloat162 h = __float22bfloat162_rn(make_float2(lo, hi));
    union { __hip_bfloat162 h; unsigned u; } v; v.h = h;
    return v.u;
}
__device__ __forceinline__ unsigned short f2bf(float f) {
    union { float f; unsigned u; } v; v.f = f;
    unsigned r = v.u + 0x7FFFu + ((v.u >> 16) & 1u);
    return (unsigned short)(r >> 16);
}
__device__ __forceinline__ float fast_sigmoid(float x) {
    return __builtin_amdgcn_rcpf(1.0f + __expf(-x));
}
__device__ __forceinline__ float fast_softplus(float x) {
    return fmaxf(x, 0.0f) + __logf(1.0f + __expf(-fabsf(x)));
}

// ---- Kernel 1: separable DFT of padded 7x7 kernels -> field[hw][c] = (Ar,Ai,Br,Bi) ----
// Stage 1 (per block, v fixed): G[kern][c][p] = sum_q k[c,p,q] * e^{-i*2pi*v*(q+60)/128}
// Stage 2: F[c,u,v] = sum_p G[kern][c][p] * e^{-i*2pi*u*(p+60)/128}
__global__ void field_kernel(const float* __restrict__ Ark, const float* __restrict__ Aik,
                             const float* __restrict__ Brk, const float* __restrict__ Bik,
                             float4* __restrict__ field) {
    __shared__ float2 tw[128];
    __shared__ float2 G[2][64][9];   // stride 9 -> balanced banks on b64 reads
    const int v = blockIdx.x >> 1;
    const int uhalf = blockIdx.x & 1;
    const int t = threadIdx.x;
    if (t < 128) {
        float ph = (float)t * (6.283185307179586f / 128.0f);
        tw[t] = make_float2(cosf(ph), sinf(ph));
    }
    __syncthreads();
    // stage 1: 896 entries (2 kern x 64 c x 7 p)
    for (int e = t; e < 896; e += 256) {
        const int kern = (e >= 448) ? 1 : 0;
        const int rem = e - kern * 448;
        const int c = rem / 7, p = rem % 7;
        const float* kr = kern ? Brk : Ark;
        const float* ki = kern ? Bik : Aik;
        float gr = 0.f, gi = 0.f;
#pragma unroll
        for (int q = 0; q < 7; ++q) {
            const int idx = (v * (q + 60)) & 127;
            const float twr = tw[idx].x, twi = -tw[idx].y;
            const float ar = kr[c * 49 + p * 7 + q], ai = ki[c * 49 + p * 7 + q];
            gr += ar * twr - ai * twi;
            gi += ar * twi + ai * twr;
        }
        G[kern][c][p] = make_float2(gr, gi);
    }
    __syncthreads();
    const int c = t & 63, ug = t >> 6;
    float2 gA[7], gB[7];
#pragma unroll
    for (int p = 0; p < 7; ++p) { gA[p] = G[0][c][p]; gB[p] = G[1][c][p]; }
    for (int k = 0; k < 16; ++k) {
        const int u = uhalf * 64 + ug * 16 + k;
        float Are = 0.f, Aim = 0.f, Bre = 0.f, Bim = 0.f;
#pragma unroll
        for (int p = 0; p < 7; ++p) {
            const int idx = (u * (p + 60)) & 127;
            const float twr = tw[idx].x, twi = -tw[idx].y;
            Are += gA[p].x * twr - gA[p].y * twi;
            Aim += gA[p].x * twi + gA[p].y * twr;
            Bre += gB[p].x * twr - gB[p].y * twi;
            Bim += gB[p].x * twi + gB[p].y * twr;
        }
        const float mag = sqrtf(Are * Are + Aim * Aim + 1e-8f);
        const float scale = 0.95f * (1.0f / (1.0f + expf(-mag))) / (mag + 1e-8f);
        field[(size_t)(u * 128 + v) * 64 + c] = make_float4(Are * scale, Aim * scale, Bre, Bim);
    }
}

// ---- Kernel 2: weights fp32 (k,n) -> bf16 transposed (g,n,k) ----
__global__ void wprep_kernel(const float* __restrict__ Wf, const float* __restrict__ Wi,
                             const float* __restrict__ Wd, ushort* __restrict__ Wt) {
    const int idx = blockIdx.x * 256 + threadIdx.x;   // 0 .. 49151
    const int g = idx >> 14;
    const int r = idx & 16383;
    const int n = r >> 7, k = r & 127;
    const float* W = (g == 0) ? Wf : (g == 1) ? Wi : Wd;
    Wt[idx] = f2bf(W[k * 128 + n]);
}

// ---- Kernel 3: fused gates-GEMM + complex SSM recurrence ----
__global__ __launch_bounds__(256, 3) void main_kernel(
    const float* __restrict__ x,
    const float* __restrict__ bfv, const float* __restrict__ biv, const float* __restrict__ bdv,
    const float4* __restrict__ field,
    const ushort* __restrict__ Wt,
    float* __restrict__ out)
{
    __shared__ ushort xb0[16][136];   // bf16 tile, stride 136 -> aligned + balanced b128
    __shared__ ushort xb1[16][136];
    const int tid  = threadIdx.x;
    const int lane = tid & 63;
    const int wave = tid >> 6;   // 0..3
    const int l15  = lane & 15;
    const int lg   = lane >> 4;  // 0..3

    // persistent weight fragments: wf[gate][half][kstep]
    bf16x8 wf[3][2][4];
#pragma unroll
    for (int g = 0; g < 3; ++g)
#pragma unroll
        for (int s = 0; s < 2; ++s) {
            const int n = l15 + 16 * (wave + 4 * s);
#pragma unroll
            for (int ks = 0; ks < 4; ++ks) {
                const int k0 = 32 * ks + 8 * lg;
                wf[g][s][ks] = *(const bf16x8*)(Wt + ((g * 128 + n) * 128 + k0));
            }
        }

    const int c0 = l15 + 16 * wave;   // real channel
    const int c1 = c0 + 64;           // imag channel
    const float bf0 = bfv[c0] + 2.0f, bf1 = bfv[c1] + 2.0f;
    const float bi0 = biv[c0], bi1 = biv[c1];
    const float bd0 = bdv[c0], bd1 = bdv[c1];

    const int srow = tid >> 4;         // staging: batch row 0..15
    const int scol = (tid & 15) * 8;   // 8 elements per thread

    const int hw0 = blockIdx.x * PPB;

    // prologue: stage pixel 0 into xb0
    {
        const float* src = x + ((size_t)srow * HW_TOTAL + hw0) * C2 + scol;
        const float4 qa = *(const float4*)src;
        const float4 qb = *(const float4*)(src + 4);
        unsigned pk[4] = { pk2bf(qa.x, qa.y), pk2bf(qa.z, qa.w),
                           pk2bf(qb.x, qb.y), pk2bf(qb.z, qb.w) };
        *(uint4*)&xb0[srow][scol] = *(uint4*)pk;
    }
    __syncthreads();

    auto body = [&](const ushort (*rb)[136], ushort (*wb)[136], int pp) {
        const int hw = hw0 + pp;

        // early loads: field vector + fp32 recurrence inputs (L1-hot) + next-pixel prefetch
        const float4 fld = field[(size_t)hw * 64 + c0];
        float xr4[4], xi4[4];
#pragma unroll
        for (int r = 0; r < 4; ++r) {
            const size_t rowo = ((size_t)(4 * lg + r) * HW_TOTAL + hw) * C2;
            xr4[r] = x[rowo + c0];
            xi4[r] = x[rowo + c1];
        }
        const bool pref = (pp + 1 < PPB);
        float4 qa, qb;
        if (pref) {
            const float* src = x + ((size_t)srow * HW_TOTAL + (hw + 1)) * C2 + scol;
            qa = *(const float4*)src;
            qb = *(const float4*)(src + 4);
        }

        // --- GEMM: 3 gates x 2 halves, K=128 ---
        f32x4 acc[3][2];
#pragma unroll
        for (int g = 0; g < 3; ++g)
#pragma unroll
            for (int s = 0; s < 2; ++s)
                acc[g][s] = (f32x4){0.f, 0.f, 0.f, 0.f};
#pragma unroll
        for (int ks = 0; ks < 4; ++ks) {
            const bf16x8 af = *(const bf16x8*)&rb[l15][8 * lg + 32 * ks];
#pragma unroll
            for (int g = 0; g < 3; ++g)
#pragma unroll
                for (int s = 0; s < 2; ++s)
                    acc[g][s] = __builtin_amdgcn_mfma_f32_16x16x32_bf16(
                        af, wf[g][s][ks], acc[g][s], 0, 0, 0);
        }

        // stage next pixel into the write buffer
        if (pref) {
            unsigned pk[4] = { pk2bf(qa.x, qa.y), pk2bf(qa.z, qa.w),
                               pk2bf(qb.x, qb.y), pk2bf(qb.z, qb.w) };
            *(uint4*)&wb[srow][scol] = *(uint4*)pk;
        }

        // --- gates + T=16 recurrence via matrix doubling ---
        const float Ar = fld.x, Ai = fld.y, Br = fld.z, Bi = fld.w;
#pragma unroll
        for (int r = 0; r < 4; ++r) {
            const int b = 4 * lg + r;
            const float fg_r = fast_sigmoid(acc[0][0][r] + bf0);
            const float fg_i = fast_sigmoid(acc[0][1][r] + bf1);
            const float ig_r = fast_sigmoid(acc[1][0][r] + bi0);
            const float ig_i = fast_sigmoid(acc[1][1][r] + bi1);
            const float dl_r = fast_softplus(acc[2][0][r] + bd0) * 0.1f;
            const float dl_i = fast_softplus(acc[2][1][r] + bd1) * 0.1f;
            float vr = dl_r * ig_r * fmaf(Br, xr4[r], -Bi * xi4[r]);
            float vi = dl_i * ig_i * fmaf(Br, xi4[r],  Bi * xr4[r]);
            // M = [[a, bm],[cm, d]]; h_16 = (I+M)(I+M^2)(I+M^4)(I+M^8) * inp
            float a  = fg_r * Ar, bm = -(fg_r * Ai);
            float cm = fg_i * Ai, d  = fg_i * Ar;
#pragma unroll
            for (int j = 0; j < 4; ++j) {
                const float nvr = fmaf(a, vr, fmaf(bm, vi, vr));
                const float nvi = fmaf(cm, vr, fmaf(d, vi, vi));
                if (j < 3) {
                    const float trc = a + d, bc = bm * cm;
                    const float na = fmaf(a, a, bc), nd = fmaf(d, d, bc);
                    const float nb = bm * trc, nc = cm * trc;
                    a = na; bm = nb; cm = nc; d = nd;
                }
                vr = nvr; vi = nvi;
            }
            const size_t obase = ((size_t)b * HW_TOTAL + hw) * C2;
            out[obase + c0] = vr;
            out[obase + c1] = vi;
        }
        __syncthreads();
    };

    for (int p2 = 0; p2 < PPB; p2 += 2) {
        body(xb0, xb1, p2);
        body(xb1, xb0, p2 + 1);
    }
}

extern "C" void kernel_launch(void* const* d_in, const int* in_sizes, int n_in,
                              void* d_out, int out_size, void* d_ws, size_t ws_size,
                              hipStream_t stream) {
    const float* x      = (const float*)d_in[0];
    const float* Wf     = (const float*)d_in[1];
    const float* bf     = (const float*)d_in[2];
    const float* Wi     = (const float*)d_in[3];
    const float* bi     = (const float*)d_in[4];
    const float* Wd     = (const float*)d_in[5];
    const float* bd     = (const float*)d_in[6];
    const float* A_real = (const float*)d_in[7];
    const float* A_imag = (const float*)d_in[8];
    const float* B_real = (const float*)d_in[9];
    const float* B_imag = (const float*)d_in[10];

    float4* field = (float4*)d_ws;                                       // 16 MiB
    ushort* Wt = (ushort*)((char*)d_ws + (size_t)HW_TOTAL * 64 * 16);    // 96 KiB

    field_kernel<<<dim3(256), dim3(256), 0, stream>>>(A_real, A_imag, B_real, B_imag, field);
    wprep_kernel<<<dim3(192), dim3(256), 0, stream>>>(Wf, Wi, Wd, Wt);
    main_kernel<<<dim3(NBLK), dim3(256), 0, stream>>>(x, bf, bi, bd, field, Wt, (float*)d_out);
}

// Round 4
// 101.484 us; speedup vs baseline: 1.4187x; 1.4187x over previous
//
#include <hip/hip_runtime.h>
#include <hip/hip_bf16.h>

#define HW_TOTAL 16384
#define C2 128
#define PPB 16
#define NBLK (HW_TOTAL / PPB)

typedef short bf16x8 __attribute__((ext_vector_type(8)));
typedef float f32x4 __attribute__((ext_vector_type(4)));

__device__ __forceinline__ unsigned pk2bf(float lo, float hi) {
    __hip_bfloat162 h = __float22bfloat162_rn(make_float2(lo, hi));
    union { __hip_bfloat162 h; unsigned u; } v; v.h = h;
    return v.u;
}
__device__ __forceinline__ unsigned short f2bf(float f) {
    union { float f; unsigned u; } v; v.f = f;
    unsigned r = v.u + 0x7FFFu + ((v.u >> 16) & 1u);
    return (unsigned short)(r >> 16);
}
__device__ __forceinline__ float fast_sigmoid(float x) {
    return __builtin_amdgcn_rcpf(1.0f + __expf(-x));
}
__device__ __forceinline__ float fast_softplus(float x) {
    return fmaxf(x, 0.0f) + __logf(1.0f + __expf(-fabsf(x)));
}

// ---- Kernel 1: separable DFT of padded 7x7 kernels -> field[hw][c] = (Ar,Ai,Br,Bi) ----
__global__ void field_kernel(const float* __restrict__ Ark, const float* __restrict__ Aik,
                             const float* __restrict__ Brk, const float* __restrict__ Bik,
                             float4* __restrict__ field) {
    __shared__ float2 tw[128];
    __shared__ float2 G[2][64][9];
    const int v = blockIdx.x >> 1;
    const int uhalf = blockIdx.x & 1;
    const int t = threadIdx.x;
    if (t < 128) {
        float ph = (float)t * (6.283185307179586f / 128.0f);
        tw[t] = make_float2(cosf(ph), sinf(ph));
    }
    __syncthreads();
    for (int e = t; e < 896; e += 256) {
        const int kern = (e >= 448) ? 1 : 0;
        const int rem = e - kern * 448;
        const int c = rem / 7, p = rem % 7;
        const float* kr = kern ? Brk : Ark;
        const float* ki = kern ? Bik : Aik;
        float gr = 0.f, gi = 0.f;
#pragma unroll
        for (int q = 0; q < 7; ++q) {
            const int idx = (v * (q + 60)) & 127;
            const float twr = tw[idx].x, twi = -tw[idx].y;
            const float ar = kr[c * 49 + p * 7 + q], ai = ki[c * 49 + p * 7 + q];
            gr += ar * twr - ai * twi;
            gi += ar * twi + ai * twr;
        }
        G[kern][c][p] = make_float2(gr, gi);
    }
    __syncthreads();
    const int c = t & 63, ug = t >> 6;
    float2 gA[7], gB[7];
#pragma unroll
    for (int p = 0; p < 7; ++p) { gA[p] = G[0][c][p]; gB[p] = G[1][c][p]; }
    for (int k = 0; k < 16; ++k) {
        const int u = uhalf * 64 + ug * 16 + k;
        float Are = 0.f, Aim = 0.f, Bre = 0.f, Bim = 0.f;
#pragma unroll
        for (int p = 0; p < 7; ++p) {
            const int idx = (u * (p + 60)) & 127;
            const float twr = tw[idx].x, twi = -tw[idx].y;
            Are += gA[p].x * twr - gA[p].y * twi;
            Aim += gA[p].x * twi + gA[p].y * twr;
            Bre += gB[p].x * twr - gB[p].y * twi;
            Bim += gB[p].x * twi + gB[p].y * twr;
        }
        const float mag = sqrtf(Are * Are + Aim * Aim + 1e-8f);
        const float scale = 0.95f * (1.0f / (1.0f + expf(-mag))) / (mag + 1e-8f);
        field[(size_t)(u * 128 + v) * 64 + c] = make_float4(Are * scale, Aim * scale, Bre, Bim);
    }
}

// ---- Kernel 2: weights fp32 (k,n) -> bf16 transposed (g,n,k) ----
__global__ void wprep_kernel(const float* __restrict__ Wf, const float* __restrict__ Wi,
                             const float* __restrict__ Wd, ushort* __restrict__ Wt) {
    const int idx = blockIdx.x * 256 + threadIdx.x;
    const int g = idx >> 14;
    const int r = idx & 16383;
    const int n = r >> 7, k = r & 127;
    const float* W = (g == 0) ? Wf : (g == 1) ? Wi : Wd;
    Wt[idx] = f2bf(W[k * 128 + n]);
}

// ---- Kernel 3: fused gates-GEMM + complex SSM recurrence (software-pipelined) ----
__global__ __launch_bounds__(256, 2) void main_kernel(
    const float* __restrict__ x,
    const float* __restrict__ bfv, const float* __restrict__ biv, const float* __restrict__ bdv,
    const float4* __restrict__ field,
    const ushort* __restrict__ Wt,
    float* __restrict__ out)
{
    __shared__ float  xsf[2][16][132];   // fp32 tile (recurrence inputs)
    __shared__ ushort xsb[2][16][136];   // bf16 tile (MFMA A-frags)
    const int tid  = threadIdx.x;
    const int lane = tid & 63;
    const int wave = tid >> 6;
    const int l15  = lane & 15;
    const int lg   = lane >> 4;

    // persistent weight fragments
    bf16x8 wf[3][2][4];
#pragma unroll
    for (int g = 0; g < 3; ++g)
#pragma unroll
        for (int s = 0; s < 2; ++s) {
            const int n = l15 + 16 * (wave + 4 * s);
#pragma unroll
            for (int ks = 0; ks < 4; ++ks)
                wf[g][s][ks] = *(const bf16x8*)(Wt + ((g * 128 + n) * 128 + 32 * ks + 8 * lg));
        }

    const int c0 = l15 + 16 * wave;
    const int c1 = c0 + 64;
    const float bia[3][2] = { { bfv[c0] + 2.0f, bfv[c1] + 2.0f },
                              { biv[c0],        biv[c1]        },
                              { bdv[c0],        bdv[c1]        } };

    const int srow = tid >> 4;
    const int scol = (tid & 15) * 8;
    const int hw0 = blockIdx.x * PPB;

    // running pointers
    const float* srcp = x + ((size_t)srow * HW_TOTAL + hw0) * C2 + scol;
    const float4* fldp = field + (size_t)hw0 * 64 + c0;
    float* op[4];
#pragma unroll
    for (int r = 0; r < 4; ++r)
        op[r] = out + ((size_t)(4 * lg + r) * HW_TOTAL + hw0) * C2 + c0;

    f32x4 accA[3][2], accB[3][2];
    float4 fldS0, fldS1;
    f32x4 xr0v, xi0v, xr1v, xi1v;
    float4 qa, qb;

    auto prefetch = [&]() {
        qa = *(const float4*)srcp;
        qb = *(const float4*)(srcp + 4);
        srcp += C2;
    };
    auto stage_write = [&](float (*wbF)[132], ushort (*wbB)[136]) {
        *(float4*)&wbF[srow][scol]     = qa;
        *(float4*)&wbF[srow][scol + 4] = qb;
        unsigned pk[4] = { pk2bf(qa.x, qa.y), pk2bf(qa.z, qa.w),
                           pk2bf(qb.x, qb.y), pk2bf(qb.z, qb.w) };
        *(uint4*)&wbB[srow][scol] = *(uint4*)pk;
    };
    auto loadcur = [&](float4& fldv, f32x4& xr4, f32x4& xi4, const float (*rbF)[132]) {
        fldv = *fldp; fldp += 64;
#pragma unroll
        for (int r = 0; r < 4; ++r) {
            xr4[r] = rbF[4 * lg + r][c0];
            xi4[r] = rbF[4 * lg + r][c1];
        }
    };
    auto do_mfma = [&](f32x4 (&acc)[3][2], const ushort (*rbB)[136]) {
#pragma unroll
        for (int g = 0; g < 3; ++g)
#pragma unroll
            for (int s = 0; s < 2; ++s) {
                const float b = bia[g][s];
                acc[g][s] = (f32x4){b, b, b, b};
            }
#pragma unroll
        for (int ks = 0; ks < 4; ++ks) {
            const bf16x8 af = *(const bf16x8*)&rbB[l15][8 * lg + 32 * ks];
#pragma unroll
            for (int g = 0; g < 3; ++g)
#pragma unroll
                for (int s = 0; s < 2; ++s)
                    acc[g][s] = __builtin_amdgcn_mfma_f32_16x16x32_bf16(
                        af, wf[g][s][ks], acc[g][s], 0, 0, 0);
        }
    };
    auto finish = [&](const f32x4 (&acc)[3][2], const float4& fldv,
                      const f32x4& xr4, const f32x4& xi4) {
        const float Ar = fldv.x, Ai = fldv.y, Br = fldv.z, Bi = fldv.w;
#pragma unroll
        for (int r = 0; r < 4; ++r) {
            const float fg_r = fast_sigmoid(acc[0][0][r]);
            const float fg_i = fast_sigmoid(acc[0][1][r]);
            const float ig_r = fast_sigmoid(acc[1][0][r]);
            const float ig_i = fast_sigmoid(acc[1][1][r]);
            const float dl_r = fast_softplus(acc[2][0][r]) * 0.1f;
            const float dl_i = fast_softplus(acc[2][1][r]) * 0.1f;
            float vr = dl_r * ig_r * fmaf(Br, xr4[r], -Bi * xi4[r]);
            float vi = dl_i * ig_i * fmaf(Br, xi4[r],  Bi * xr4[r]);
            float a  = fg_r * Ar, bm = -(fg_r * Ai);
            float cm = fg_i * Ai, d  = fg_i * Ar;
#pragma unroll
            for (int j = 0; j < 4; ++j) {
                const float nvr = fmaf(a, vr, fmaf(bm, vi, vr));
                const float nvi = fmaf(cm, vr, fmaf(d, vi, vi));
                if (j < 3) {
                    const float trc = a + d, bc = bm * cm;
                    const float na = fmaf(a, a, bc), nd = fmaf(d, d, bc);
                    const float nb = bm * trc, nc = cm * trc;
                    a = na; bm = nb; cm = nc; d = nd;
                }
                vr = nvr; vi = nvi;
            }
            op[r][0]  = vr;
            op[r][64] = vi;
            op[r] += C2;
        }
    };

    // prologue: stage pixel 0
    prefetch();
    stage_write(xsf[0], xsb[0]);
    __syncthreads();

    // body p=0: mfma(0)->A, stage(1)
    loadcur(fldS0, xr0v, xi0v, xsf[0]);
    prefetch();
    do_mfma(accA, xsb[0]);
    stage_write(xsf[1], xsb[1]);
    __syncthreads();

    // body p=1: mfma(1)->B, finish(0), stage(2)
    loadcur(fldS1, xr1v, xi1v, xsf[1]);
    prefetch();
    do_mfma(accB, xsb[1]);
    finish(accA, fldS0, xr0v, xi0v);
    stage_write(xsf[0], xsb[0]);
    __syncthreads();

    for (int p2 = 2; p2 < PPB; p2 += 2) {
        // even body p2: read buf0, mfma->A, finish B (pixel p2-1), stage(p2+1)->buf1
        loadcur(fldS0, xr0v, xi0v, xsf[0]);
        prefetch();
        do_mfma(accA, xsb[0]);
        finish(accB, fldS1, xr1v, xi1v);
        stage_write(xsf[1], xsb[1]);
        __syncthreads();
        // odd body p2+1: read buf1, mfma->B, finish A (pixel p2), stage(p2+2)->buf0
        loadcur(fldS1, xr1v, xi1v, xsf[1]);
        const bool pref = (p2 + 2 < PPB);
        if (pref) prefetch();
        do_mfma(accB, xsb[1]);
        finish(accA, fldS0, xr0v, xi0v);
        if (pref) stage_write(xsf[0], xsb[0]);
        __syncthreads();
    }

    // epilogue: finish last pixel
    finish(accB, fldS1, xr1v, xi1v);
}

extern "C" void kernel_launch(void* const* d_in, const int* in_sizes, int n_in,
                              void* d_out, int out_size, void* d_ws, size_t ws_size,
                              hipStream_t stream) {
    const float* x      = (const float*)d_in[0];
    const float* Wf     = (const float*)d_in[1];
    const float* bf     = (const float*)d_in[2];
    const float* Wi     = (const float*)d_in[3];
    const float* bi     = (const float*)d_in[4];
    const float* Wd     = (const float*)d_in[5];
    const float* bd     = (const float*)d_in[6];
    const float* A_real = (const float*)d_in[7];
    const float* A_imag = (const float*)d_in[8];
    const float* B_real = (const float*)d_in[9];
    const float* B_imag = (const float*)d_in[10];

    float4* field = (float4*)d_ws;                                       // 16 MiB
    ushort* Wt = (ushort*)((char*)d_ws + (size_t)HW_TOTAL * 64 * 16);    // 96 KiB

    field_kernel<<<dim3(256), dim3(256), 0, stream>>>(A_real, A_imag, B_real, B_imag, field);
    wprep_kernel<<<dim3(192), dim3(256), 0, stream>>>(Wf, Wi, Wd, Wt);
    main_kernel<<<dim3(NBLK), dim3(256), 0, stream>>>(x, bf, bi, bd, field, Wt, (float*)d_out);
}